// Round 4
// baseline (35.498 us; speedup 1.0000x reference)
//
#include <hip/hip_runtime.h>
#include <math.h>

constexpr int N_RAYS = 65536;
constexpr int NBLK   = 2048;     // 2048 blocks * 4 waves = 8192 waves
constexpr int WAVES  = NBLK * 4;

// DPP helper: lanes with a valid source get dpp(src); invalid lanes keep `oldv`.
// (row = 16 lanes; row_shr:n = lane i reads lane i-n; row_shl:n = lane i+n)
template<int CTRL>
__device__ __forceinline__ float dppf(float oldv, float x) {
    return __int_as_float(__builtin_amdgcn_update_dpp(
        __float_as_int(oldv), __float_as_int(x), CTRL, 0xF, 0xF, false));
}

__device__ __forceinline__ float row16_sum(float x) {
    x += dppf<0xB1>(0.0f, x);    // quad_perm(1,0,3,2)
    x += dppf<0x4E>(0.0f, x);    // quad_perm(2,3,0,1)
    x += dppf<0x141>(0.0f, x);   // row_half_mirror
    x += dppf<0x140>(0.0f, x);   // row_mirror
    return x;
}
__device__ __forceinline__ float row16_prod(float x) {
    x *= dppf<0xB1>(1.0f, x);
    x *= dppf<0x4E>(1.0f, x);
    x *= dppf<0x141>(1.0f, x);
    x *= dppf<0x140>(1.0f, x);
    return x;
}

// One wave = 4 rays (16 lanes/ray). STRIDED ownership: lane m owns samples
// {16j+m} per 64-sample half -> every global load is stride-1 across lanes
// (minimal cache-line transactions). Scan: per 16-sample chunk, DPP inclusive
// scan + DPP butterfly total (carry needs no broadcast). No LDS, no bpermute
// in the hot path.
__global__ __launch_bounds__(256) void integrate_kernel(
    const float* __restrict__ raw,     // [N][128][4]
    const float* __restrict__ zvals,   // [N][128]
    const float* __restrict__ rays_d,  // [N][3]
    float* __restrict__ chs_map,       // [N][3]
    float* __restrict__ depth_map,     // [N]
    float* __restrict__ block_partials)
{
    const int lane = threadIdx.x & 63;
    const int warp = threadIdx.x >> 6;
    const int g    = lane >> 4;   // ray within wave
    const int m    = lane & 15;   // lane within ray group

    float ent_acc = 0.0f;
    const int gw = blockIdx.x * 4 + warp;

    #pragma unroll
    for (int k = 0; k < 2; ++k) {
        const int ray = (gw + k * WAVES) * 4 + g;

        const float* rd = rays_d + (size_t)ray * 3;
        const float norm = sqrtf(rd[0]*rd[0] + rd[1]*rd[1] + rd[2]*rd[2]);

        // z: 8 coalesced scalar loads (chunk jj, lane m -> z[16*jj + m])
        const float* zr = zvals + (size_t)ray * 128;
        float z[8];
        #pragma unroll
        for (int jj = 0; jj < 8; ++jj) z[jj] = zr[16*jj + m];

        const float4* rq = (const float4*)raw + (size_t)ray * 128;

        float c0=0.f, c1=0.f, c2=0.f, wsum=0.f, dnum=0.f, aa=0.f;
        float carry = 1.0f;

        #pragma unroll
        for (int h = 0; h < 2; ++h) {
            // raw: stride-1 across lanes (lane m -> sample h*64 + 16j + m)
            float4 q[4];
            #pragma unroll
            for (int j = 0; j < 4; ++j) q[j] = rq[h*64 + 16*j + m];

            #pragma unroll
            for (int j = 0; j < 4; ++j) {
                const int jj = h*4 + j;
                const float zc = z[jj];
                // z[s+1]: lanes 0..14 via row_shl:1; lane 15 gets next chunk's
                // lane-0 value via row_shr:15 (jj==7 lane15 is overridden below)
                const float znfix = dppf<0x11F>(zc, z[(jj < 7) ? jj+1 : jj]);
                const float zn    = dppf<0x101>(znfix, zc);
                const bool  last  = (jj == 7) && (m == 15);   // s == 127
                const float dn    = last ? (1e10f * norm) : ((zn - zc) * norm);

                const float sig   = fmaxf(q[j].w, 0.0f);
                const float e     = __expf(-sig * dn);
                const float alpha = 1.0f - e;
                const float t     = e + 1e-10f;

                // inclusive product scan over the 16-lane chunk
                float sc = t;
                sc *= dppf<0x111>(1.0f, sc);   // row_shr:1
                sc *= dppf<0x112>(1.0f, sc);   // row_shr:2
                sc *= dppf<0x114>(1.0f, sc);   // row_shr:4
                sc *= dppf<0x118>(1.0f, sc);   // row_shr:8
                const float E = dppf<0x111>(1.0f, sc);   // exclusive (lane0=1)
                const float T = row16_prod(t);           // chunk total, all lanes

                const float trans = carry * E;
                const float w     = alpha * trans;
                c0   += w * q[j].x;
                c1   += w * q[j].y;
                c2   += w * q[j].z;
                wsum += w;
                dnum += w * (6.0f - zc) * 0.25f;
                aa   += (w > 0.0f) ? w * __logf(w) : 0.0f;
                carry *= T;
            }
        }

        // 6-var allreduce within the 16-lane group (pure DPP)
        c0   = row16_sum(c0);
        c1   = row16_sum(c1);
        c2   = row16_sum(c2);
        wsum = row16_sum(wsum);
        dnum = row16_sum(dnum);
        aa   = row16_sum(aa);

        if (m == 0) {
            chs_map[(size_t)ray * 3 + 0] = c0;
            chs_map[(size_t)ray * 3 + 1] = c1;
            chs_map[(size_t)ray * 3 + 2] = c2;
            depth_map[ray] = dnum / (wsum + 1e-5f);

            // sum p*log p = (A - W*log(psum) + L*(log L - log psum)) / psum
            const float L = 1.0f - wsum + 1e-6f;
            const float psum = wsum + L;
            const float logpsum = __logf(psum);
            const float entL = (L > 0.0f) ? L * (__logf(L) - logpsum) : 0.0f;
            ent_acc -= (aa - wsum * logpsum + entL) / psum;
        }
    }

    // entropy partials live on lanes 0,16,32,48; wave reduce then block combine
    #pragma unroll
    for (int d = 1; d < 64; d <<= 1)
        ent_acc += __shfl_xor(ent_acc, d);

    __shared__ float sred[4];
    if (lane == 0) sred[warp] = ent_acc;
    __syncthreads();
    if (threadIdx.x == 0) {
        float s = 0.0f;
        #pragma unroll
        for (int i = 0; i < 4; ++i) s += sred[i];
        block_partials[blockIdx.x] = s;
    }
}

__global__ __launch_bounds__(256) void reduce_kernel(
    const float* __restrict__ partials, int n, float* __restrict__ out_scalar)
{
    float s = 0.0f;
    for (int i = threadIdx.x; i < n; i += 256) s += partials[i];
    #pragma unroll
    for (int mm = 32; mm >= 1; mm >>= 1) s += __shfl_xor(s, mm);
    __shared__ float sr[4];
    const int lane = threadIdx.x & 63;
    const int warp = threadIdx.x >> 6;
    if (lane == 0) sr[warp] = s;
    __syncthreads();
    if (threadIdx.x == 0) {
        float t = 0.0f;
        #pragma unroll
        for (int i = 0; i < 4; ++i) t += sr[i];
        *out_scalar = t;
    }
}

extern "C" void kernel_launch(void* const* d_in, const int* in_sizes, int n_in,
                              void* d_out, int out_size, void* d_ws, size_t ws_size,
                              hipStream_t stream) {
    const float* raw    = (const float*)d_in[0];
    const float* zvals  = (const float*)d_in[1];
    const float* rays_d = (const float*)d_in[2];

    float* out = (float*)d_out;
    float* chs_map   = out;                       // 65536*3
    float* depth_map = out + (size_t)N_RAYS * 3;  // 65536
    float* sparsity  = out + (size_t)N_RAYS * 4;  // 1

    float* partials = (float*)d_ws;               // NBLK floats

    integrate_kernel<<<NBLK, 256, 0, stream>>>(raw, zvals, rays_d,
                                               chs_map, depth_map, partials);
    reduce_kernel<<<1, 256, 0, stream>>>(partials, NBLK, sparsity);
}